// Round 1
// baseline (168.966 us; speedup 1.0000x reference)
//
#include <hip/hip_runtime.h>
#include <hip/hip_bf16.h>

#define NN 4096
#define IN_DIM 512
#define NH 8
#define DD 64
#define HD 512    // NH*DD
#define RCAP 448  // per-row cap: mean 205 sigma 14 -> +17 sigma
#define GEMM_WGS 512
#define SCAN_WGS 1024
#define LOG2E 1.4426950408889634f

// Workspace: d1b 4MB + Ab 4MB + Wb 0.5MB + src/trg 0.25MB + bm 2MB = 10.75 MB
// (R3 lesson: stay well under ~12 MB; R7 proved 8.75 MB works; +2MB bitmask ok).

typedef __attribute__((ext_vector_type(8))) short short8;
typedef __attribute__((ext_vector_type(4))) float f32x4;
typedef __attribute__((ext_vector_type(2))) float f32x2;

static __device__ __forceinline__ unsigned short f2bf(float x) {
    __hip_bfloat16 h = __float2bfloat16(x);
    return *reinterpret_cast<unsigned short*>(&h);
}

// ---------------- K0: fp32 -> bf16 cast of data and W (one launch) -----------
// Cast ONCE here; R8 fused the cast into the GEMM and paid 64x-redundant
// per-fragment conversion VALU — that was a 20 us regression.
__global__ __launch_bounds__(256) void k_cast2(const float* __restrict__ inA,
                                               unsigned short* __restrict__ outA,
                                               int n4A,
                                               const float* __restrict__ inB,
                                               unsigned short* __restrict__ outB,
                                               int n4B) {
    int t = blockIdx.x * 256 + threadIdx.x;
    const float* in;
    unsigned short* out;
    if (t < n4A) {
        in = inA; out = outA;
    } else {
        t -= n4A;
        if (t >= n4B) return;
        in = inB; out = outB;
    }
    float4 v = ((const float4*)in)[t];
    ushort4 o;
    o.x = f2bf(v.x); o.y = f2bf(v.y); o.z = f2bf(v.z); o.w = f2bf(v.w);
    ((ushort4*)out)[t] = o;
}

// ---------------- K1: GEMM (bf16 MFMA) + fused src/trg projection ------------
//                      + conn edge-bitmask scan in the SAME grid.
// Blocks [0,512): 64n x 64m GEMM tile; m-tile == head h. Blocks [512,1536):
// each wave ballot-scans one conn row into a 64-word bitmask (2MB total).
// Rationale: GEMM alone is 512 WGs = 2 waves/SIMD (latency-starved, L2-bound);
// the scan is pure HBM (64MB). Same grid -> the HBM read hides under MFMA and
// the extra 4096 waves fill the idle SIMD slots. Same-stream separate kernels
// would serialize instead.
// src/trg are pre-scaled by LOG2E so k_rowattn can use a bare v_exp_f32:
// exp(leaky(s+t)) == exp2(leaky(s*c + t*c)) since leaky(c*x)=c*leaky(x), c>0.
__global__ __launch_bounds__(256) void k_gemm_scan(const unsigned short* __restrict__ Ab,
                                                   const unsigned short* __restrict__ Wb,
                                                   const float* __restrict__ bias,
                                                   const float* __restrict__ sp,
                                                   const float* __restrict__ tp,
                                                   const float* __restrict__ conn,
                                                   unsigned short* __restrict__ Cb,
                                                   float* __restrict__ src,
                                                   float* __restrict__ trg,
                                                   unsigned long long* __restrict__ bm) {
    const int lane = threadIdx.x & 63;
    const int w = threadIdx.x >> 6;

    if (blockIdx.x >= GEMM_WGS) {
        // ---- conn scan path: one row per wave, 64-bit word per 64 columns ----
        const int row = (blockIdx.x - GEMM_WGS) * 4 + w;
        const float* crow = conn + (size_t)row * NN;
        unsigned long long keep = 0;
#pragma unroll 8
        for (int t = 0; t < 64; t++) {
            float c = crow[t * 64 + lane];                 // 256B coalesced
            unsigned long long m = __ballot(c == 0.0f);    // kept edge == 0.0f
            if (lane == t) keep = m;
        }
        bm[(size_t)row * 64 + lane] = keep;                // 512B coalesced
        return;
    }

    // ---- GEMM path (unchanged math; blockIdx remapped to 1D) ----
    const int col = lane & 15;
    const int quad = lane >> 4;
    const int koff = quad * 8;
    const int h = blockIdx.x & 7;
    const int m0 = h * 64;
    const int n0 = (blockIdx.x >> 3) * 64;

    const short8* ap  = (const short8*)(Ab + (size_t)(n0 + w * 16 + col) * IN_DIM + koff);
    const short8* bp0 = (const short8*)(Wb + (size_t)(m0 +  0 + col) * IN_DIM + koff);
    const short8* bp1 = (const short8*)(Wb + (size_t)(m0 + 16 + col) * IN_DIM + koff);
    const short8* bp2 = (const short8*)(Wb + (size_t)(m0 + 32 + col) * IN_DIM + koff);
    const short8* bp3 = (const short8*)(Wb + (size_t)(m0 + 48 + col) * IN_DIM + koff);

    f32x4 acc0 = {0.f, 0.f, 0.f, 0.f}, acc1 = acc0, acc2 = acc0, acc3 = acc0;

#pragma unroll 4
    for (int ks = 0; ks < 16; ks++) {
        short8 a  = ap[ks * 4];
        short8 b0 = bp0[ks * 4];
        short8 b1 = bp1[ks * 4];
        short8 b2 = bp2[ks * 4];
        short8 b3 = bp3[ks * 4];
        acc0 = __builtin_amdgcn_mfma_f32_16x16x32_bf16(a, b0, acc0, 0, 0, 0);
        acc1 = __builtin_amdgcn_mfma_f32_16x16x32_bf16(a, b1, acc1, 0, 0, 0);
        acc2 = __builtin_amdgcn_mfma_f32_16x16x32_bf16(a, b2, acc2, 0, 0, 0);
        acc3 = __builtin_amdgcn_mfma_f32_16x16x32_bf16(a, b3, acc3, 0, 0, 0);
    }

    const int rbase = n0 + w * 16 + quad * 4;
    f32x4 accs[4] = {acc0, acc1, acc2, acc3};
    float ps[4] = {0.f, 0.f, 0.f, 0.f};
    float pt[4] = {0.f, 0.f, 0.f, 0.f};
#pragma unroll
    for (int mt = 0; mt < 4; mt++) {
        const int m = m0 + mt * 16 + col;
        const float bv  = bias[m];
        const float spv = sp[m];
        const float tpv = tp[m];
#pragma unroll
        for (int r = 0; r < 4; r++) {
            float v = accs[mt][r] + bv;
            Cb[(size_t)(rbase + r) * HD + m] = f2bf(v);
            ps[r] += v * spv;
            pt[r] += v * tpv;
        }
    }
#pragma unroll
    for (int off = 1; off <= 8; off <<= 1) {
#pragma unroll
        for (int r = 0; r < 4; r++) {
            ps[r] += __shfl_xor(ps[r], off, 64);
            pt[r] += __shfl_xor(pt[r], off, 64);
        }
    }
    if (col < 4)
        src[(rbase + col) * 8 + h] = ps[col] * LOG2E;
    else if (col < 8)
        trg[(rbase + col - 4) * 8 + h] = pt[col - 4] * LOG2E;
}

// ---------------- K2: bitmask-expand + balanced gather attention -------------
// Phase 1: 64 threads load the 512B row bitmask, popcll + wave prefix-scan,
//          bit-extract straight into the ordered LDS elist (+8 sentinels).
//          (Replaces the 16KB/row conn ballot scan — 64MB HBM removed.)
// Phase 2: balanced per-wave gather, f32x2 packed accumulate of the 1KB bf16
//          V row + inline denominator; p = v_exp_f32 directly (src/trg carry
//          the LOG2E factor).
// Phase 3: LDS combine, divide once, store.
__global__ __launch_bounds__(256) void k_rowattn(const unsigned long long* __restrict__ bm,
                                                 const float* __restrict__ src,
                                                 const float* __restrict__ trg,
                                                 const unsigned short* __restrict__ d1b,
                                                 float* __restrict__ out) {
    __shared__ unsigned short elist[RCAP + 8];
    __shared__ int sTot;
    __shared__ float cbuf[3][64][9];   // waves 1..3 deposit acc[8]+lsum
    const int w = threadIdx.x >> 6, lane = threadIdx.x & 63;
    const int i = blockIdx.x;
    const int h = lane >> 3, d8 = lane & 7;

    // ---- phase 1: expand bitmask into contiguous ordered edge list ----
    if (threadIdx.x < 64) {
        unsigned long long m = bm[(size_t)i * 64 + lane];
        const int cnt = __popcll(m);
        int pre = cnt;
#pragma unroll
        for (int off = 1; off < 64; off <<= 1) {
            int v = __shfl_up(pre, off, 64);
            if (lane >= off) pre += v;
        }
        int tot = __shfl(pre, 63, 64);
        int pos = pre - cnt;               // exclusive prefix
        const int base = lane * 64;
        while (m) {                        // avg 3.2 bits/lane, max ~14
            int b = __builtin_ctzll(m);
            m &= m - 1;
            if (pos < RCAP) elist[pos] = (unsigned short)(base + b);
            pos++;
        }
        if (tot > RCAP) tot = RCAP;        // unreachable in practice
        unsigned short sv = (tot > 0) ? elist[tot - 1] : (unsigned short)0;
        if (lane < 8) elist[tot + lane] = sv;   // sentinels: prefetch needs no clamp
        if (lane == 0) sTot = tot;
    }
    __syncthreads();
    const int tot = sTot;

    // ---- phase 2: balanced gather, packed accumulate ----
    const float sh = src[i * 8 + h];
    const unsigned voffB = (unsigned)(h * 64 + d8 * 8) * 2u;
    const unsigned toffB = (unsigned)h << 2;
    const unsigned char* vb = (const unsigned char*)d1b;
    const unsigned char* tb = (const unsigned char*)trg;
    const int kbeg = (tot * w) >> 2;
    const int kend = (tot * (w + 1)) >> 2;

    f32x2 a01 = {0.f, 0.f}, a23 = a01, a45 = a01, a67 = a01;
    float lsum = 0.f;
    if (kend > kbeg) {
        unsigned j0 = elist[kbeg];
        unsigned j1 = elist[kbeg + 1];
        unsigned j2 = elist[kbeg + 2];
        float t0 = *(const float*)(tb + (j0 << 5) + toffB);
        float t1 = *(const float*)(tb + (j1 << 5) + toffB);
        uint4 U0 = *(const uint4*)(vb + (j0 << 10) + voffB);
        uint4 U1 = *(const uint4*)(vb + (j1 << 10) + voffB);
#pragma unroll 3
        for (int k = kbeg; k < kend; k++) {
            unsigned j3 = elist[k + 3];          // sentinel-padded: no clamp
            float t2 = *(const float*)(tb + (j2 << 5) + toffB);
            uint4 U2 = *(const uint4*)(vb + (j2 << 10) + voffB);
            float e = sh + t0;
            e = fmaxf(e, 0.01f * e);             // LeakyReLU (scale-commuted)
            float p = __builtin_amdgcn_exp2f(e); // == exp(orig e)
            lsum += p;
            f32x2 p2 = {p, p};
            f32x2 v01 = {__uint_as_float(U0.x << 16), __uint_as_float(U0.x & 0xffff0000u)};
            f32x2 v23 = {__uint_as_float(U0.y << 16), __uint_as_float(U0.y & 0xffff0000u)};
            f32x2 v45 = {__uint_as_float(U0.z << 16), __uint_as_float(U0.z & 0xffff0000u)};
            f32x2 v67 = {__uint_as_float(U0.w << 16), __uint_as_float(U0.w & 0xffff0000u)};
            a01 += p2 * v01;                     // v_pk_fma_f32
            a23 += p2 * v23;
            a45 += p2 * v45;
            a67 += p2 * v67;
            t0 = t1; t1 = t2;
            U0 = U1; U1 = U2;
            j2 = j3;
        }
    }

    // ---- phase 3: combine 4 wave-partials, normalize, store ----
    float acc[8] = {a01.x, a01.y, a23.x, a23.y, a45.x, a45.y, a67.x, a67.y};
    if (w > 0) {
#pragma unroll
        for (int r = 0; r < 8; r++) cbuf[w - 1][lane][r] = acc[r];
        cbuf[w - 1][lane][8] = lsum;
    }
    __syncthreads();
    if (w == 0) {
#pragma unroll
        for (int wv = 0; wv < 3; wv++) {
#pragma unroll
            for (int r = 0; r < 8; r++) acc[r] += cbuf[wv][lane][r];
            lsum += cbuf[wv][lane][8];
        }
        float inv = (lsum > 0.f) ? (1.f / lsum) : 0.f;
        float* op = out + (size_t)i * HD + h * 64 + d8 * 8;
        *(float4*)op = make_float4(acc[0] * inv, acc[1] * inv, acc[2] * inv, acc[3] * inv);
        *(float4*)(op + 4) = make_float4(acc[4] * inv, acc[5] * inv, acc[6] * inv, acc[7] * inv);
    }
}

extern "C" void kernel_launch(void* const* d_in, const int* in_sizes, int n_in,
                              void* d_out, int out_size, void* d_ws, size_t ws_size,
                              hipStream_t stream) {
    const float* data = (const float*)d_in[0];   // (4096, 512)
    const float* conn = (const float*)d_in[1];   // (4096, 4096)
    const float* W    = (const float*)d_in[2];   // (512, 512)
    const float* bias = (const float*)d_in[3];   // (512,)
    const float* sp   = (const float*)d_in[4];   // (1, 8, 64)
    const float* tp   = (const float*)d_in[5];   // (1, 8, 64)
    float* out = (float*)d_out;                  // (4096, 512) fp32

    unsigned short* d1b = (unsigned short*)d_ws;              // 2M bf16 (4 MB)
    unsigned short* Ab  = d1b + (size_t)NN * HD;              // 2M bf16 (4 MB)
    unsigned short* Wb  = Ab + (size_t)NN * IN_DIM;           // 256K bf16 (512 KB)
    float* src  = (float*)(Wb + (size_t)HD * IN_DIM);         // 128 KB
    float* trg  = src + NN * NH;                              // 128 KB
    unsigned long long* bm = (unsigned long long*)(trg + NN * NH); // 2 MB (8B-aligned)
    // total ~10.75 MB

    const int n4A = NN * IN_DIM / 4;   // 524288
    const int n4B = HD * IN_DIM / 4;   // 65536
    k_cast2<<<dim3((n4A + n4B + 255) / 256), 256, 0, stream>>>(data, Ab, n4A, W, Wb, n4B);
    k_gemm_scan<<<dim3(GEMM_WGS + SCAN_WGS), 256, 0, stream>>>(Ab, Wb, bias, sp, tp, conn,
                                                               d1b, src, trg, bm);
    k_rowattn<<<dim3(NN), 256, 0, stream>>>(bm, src, trg, d1b, out);
}